// Round 1
// 746.942 us; speedup vs baseline: 1.1911x; 1.1911x over previous
//
#include <hip/hip_runtime.h>
#include <hip/hip_bf16.h>
#include <math.h>

#define B_ 16
#define C_IN 64
#define C_OUT 64
#define H_ 256
#define W_ 256
#define NK 4
#define NGROUPS 8
#define CH_PER_G (C_OUT / NGROUPS)

#define WM16_SHORTS (B_ * C_OUT * 9 * C_IN)       // 589824 bf16, [b][o][tap][i]
#define WM16_BYTES (WM16_SHORTS * 2)              // 1,179,648
#define STATS_FLOATS (B_ * NGROUPS * 2)           // 256

// padded NHWC bf16 x: [b][258][258][64]
#define XT_PIX (258 * 258)                        // 66564
#define XT_OFF ((size_t)(WM16_BYTES + 4096))
#define XT_BYTES ((size_t)B_ * XT_PIX * 64 * 2)   // 136,323,072

typedef __attribute__((ext_vector_type(8))) short bf16x8;
typedef __attribute__((ext_vector_type(4))) float f32x4;
typedef unsigned int u32;

static __device__ __forceinline__ unsigned bf16bits(float v) {
    return (unsigned)__builtin_bit_cast(unsigned short, __float2bfloat16(v));
}

static __device__ __forceinline__ void load_lds16(const unsigned short* g, void* l) {
    __builtin_amdgcn_global_load_lds(
        (const __attribute__((address_space(1))) u32*)g,
        (__attribute__((address_space(3))) u32*)l, 16, 0, 0);
}

// ---------------------------------------------------------------------------
// Kernel 1: blend(softmax) + modulate + demodulate, output bf16 [b][o][tap][i]
// ---------------------------------------------------------------------------
__global__ __launch_bounds__(64)
void k_weights(const float* __restrict__ mod, const float* __restrict__ kmod,
               const float* __restrict__ cw, unsigned short* __restrict__ wm16) {
    int bo = blockIdx.x;
    int b = bo >> 6, o = bo & 63;
    int lane = threadIdx.x;   // input channel i

    float a0 = kmod[b * NK + 0], a1 = kmod[b * NK + 1];
    float a2 = kmod[b * NK + 2], a3 = kmod[b * NK + 3];
    float m = fmaxf(fmaxf(a0, a1), fmaxf(a2, a3));
    float e0 = __expf(a0 - m), e1 = __expf(a1 - m);
    float e2 = __expf(a2 - m), e3 = __expf(a3 - m);
    float inv = 1.0f / (e0 + e1 + e2 + e3);
    e0 *= inv; e1 *= inv; e2 *= inv; e3 *= inv;

    float modv = mod[b * C_IN + lane] + 1.0f;

    float wv[9];
    float ss = 0.0f;
#pragma unroll
    for (int j = 0; j < 9; ++j) {
        int idx = o * 576 + lane * 9 + j;
        float w = cw[0 * C_OUT * 576 + idx] * e0
                + cw[1 * C_OUT * 576 + idx] * e1
                + cw[2 * C_OUT * 576 + idx] * e2
                + cw[3 * C_OUT * 576 + idx] * e3;
        w *= modv;
        wv[j] = w;
        ss += w * w;
    }
#pragma unroll
    for (int off = 32; off > 0; off >>= 1)
        ss += __shfl_xor(ss, off, 64);
    float invn = rsqrtf(fmaxf(ss, 1e-8f));
#pragma unroll
    for (int j = 0; j < 9; ++j)
        wm16[((b * 64 + o) * 9 + j) * 64 + lane] =
            (unsigned short)bf16bits(wv[j] * invn);
}

// ---------------------------------------------------------------------------
// Kernel 1b: zero the 1-px border of the padded NHWC bf16 buffer.
// 16448 border pixels * 128 B = 8 chunks of 16 B each -> 131584 threads.
// ---------------------------------------------------------------------------
__global__ __launch_bounds__(256)
void k_border(unsigned short* __restrict__ xt) {
    int t = blockIdx.x * 256 + threadIdx.x;   // 0 .. 131583
    int chunk = t & 7;
    int p = t >> 3;                           // 0 .. 16447
    int b = p / 1028;
    int pid = p - b * 1028;
    int r, c;
    if (pid < 258)      { r = 0;             c = pid; }
    else if (pid < 516) { r = 257;           c = pid - 258; }
    else if (pid < 772) { r = pid - 516 + 1; c = 0; }
    else                { r = pid - 772 + 1; c = 257; }
    *(int4*)((char*)xt + (size_t)(b * XT_PIX + r * 258 + c) * 128 + chunk * 16) =
        make_int4(0, 0, 0, 0);
}

// ---------------------------------------------------------------------------
// Kernel 1c: transpose x NCHW fp32 -> padded NHWC bf16.
// Block: one (b, h) row, 128-px segment. Wave covers 32 px x 64 ch so each
// channel's 128 B cache line is fully consumed by its own wave.
// Loads: float4 (16 B/lane). Stores: 2 B/lane, 64 lanes contiguous = 128 B/instr.
// ---------------------------------------------------------------------------
__global__ __launch_bounds__(256)
void k_xpose(const float* __restrict__ x, unsigned short* __restrict__ xt) {
    const int bx  = blockIdx.x;               // 16 b * 256 h * 2 seg = 8192
    const int seg = bx & 1;
    const int h   = (bx >> 1) & 255;
    const int b   = bx >> 9;
    const int c   = threadIdx.x & 63;
    const int wv  = threadIdx.x >> 6;
    const int p0  = seg * 128 + wv * 32;      // starting pixel column
    const float* xp = x + (((b * 64 + c) * 256 + h) * 256 + p0);
    unsigned short* op = xt + ((size_t)(b * 258 + h + 1) * 258 + p0 + 1) * 64 + c;
#pragma unroll
    for (int j = 0; j < 8; ++j) {
        float4 v = *(const float4*)(xp + j * 4);
        op[(j * 4 + 0) * 64] = (unsigned short)bf16bits(v.x);
        op[(j * 4 + 1) * 64] = (unsigned short)bf16bits(v.y);
        op[(j * 4 + 2) * 64] = (unsigned short)bf16bits(v.z);
        op[(j * 4 + 3) * 64] = (unsigned short)bf16bits(v.w);
    }
}

// ---------------------------------------------------------------------------
// Kernel 2 (fast path): implicit-GEMM conv via MFMA bf16.
// Staging is now pure async DMA: 11 global_load_lds dwordx4 per thread from
// the padded NHWC bf16 buffer. Per-lane SOURCE address carries the
// chunk^(slot&7) swizzle; LDS destination is linear (m104/m173 rule).
// Main MFMA loop identical to the verified baseline.
// ---------------------------------------------------------------------------
#define NSLOT 340           // 10 * 34 real slots
#define SLOTPAD 352         // padded so 352*8 / 256 = 11 exact iterations

__global__ __launch_bounds__(256, 3)
void k_conv2(const unsigned short* __restrict__ xt,
             const unsigned short* __restrict__ wm16,
             float* __restrict__ y, float* __restrict__ stats) {
    __shared__ __align__(16) char smem[SLOTPAD * 128];
    __shared__ float lst[16];

    const int tile = blockIdx.x;          // 0..255
    const int b    = blockIdx.y;          // 0..15
    const int R0   = (tile >> 3) * 8;
    const int C0   = (tile & 7) * 32;
    const int tid  = threadIdx.x;
    const int w    = tid >> 6;            // wave 0..3
    const int lane = tid & 63;
    const int l15  = lane & 15;
    const int q    = lane >> 4;           // 0..3

    if (tid < 16) lst[tid] = 0.0f;

    // ---- stage X: async global->LDS, zero VALU conversion ----
    const unsigned short* xb = xt + (size_t)b * (XT_PIX * 64);
#pragma unroll
    for (int k = 0; k < 11; ++k) {
        int t = k * 256 + tid;
        int slot = t >> 3;                         // padded slot 0..351
        int p = t & 7;                             // LDS chunk position
        int s = slot < NSLOT ? slot : NSLOT - 1;   // clamp dups (never read)
        int r = s / 34;
        int c = s - r * 34;
        int srcchunk = p ^ (s & 7);                // pre-swizzled source
        const unsigned short* src = xb + (((R0 + r) * 258 + (C0 + c)) * 64 + srcchunk * 8);
        load_lds16(src, smem + t * 16);
    }
    __syncthreads();

    // ---- MFMA main loop: 9 taps x 2 k-chunks of 32 channels ----
    f32x4 acc[4][4];
#pragma unroll
    for (int mt = 0; mt < 4; ++mt)
#pragma unroll
        for (int nt = 0; nt < 4; ++nt)
            acc[mt][nt] = (f32x4){0.f, 0.f, 0.f, 0.f};

    const unsigned short* wb = wm16 + b * (64 * 9 * 64);

    for (int tap = 0; tap < 9; ++tap) {
        const int ky = tap / 3;
        const int kx = tap - ky * 3;

        bf16x8 af[4][2];
#pragma unroll
        for (int mt = 0; mt < 4; ++mt)
#pragma unroll
            for (int kc = 0; kc < 2; ++kc)
                af[mt][kc] = *(const bf16x8*)(wb +
                    ((mt * 16 + l15) * 9 + tap) * 64 + kc * 32 + q * 8);

#pragma unroll
        for (int kc = 0; kc < 2; ++kc) {
            bf16x8 bfr[4];
#pragma unroll
            for (int nt = 0; nt < 4; ++nt) {
                int ro = 2 * w + (nt >> 1);          // output row in tile
                int c0 = (nt & 1) * 16;              // col half
                int slot = (ro + ky) * 34 + c0 + kx + l15;
                int chunk = kc * 4 + q;
                bfr[nt] = *(const bf16x8*)(smem + slot * 128 +
                                           ((chunk ^ (slot & 7)) << 4));
            }
#pragma unroll
            for (int mt = 0; mt < 4; ++mt)
#pragma unroll
                for (int nt = 0; nt < 4; ++nt)
                    acc[mt][nt] = __builtin_amdgcn_mfma_f32_16x16x32_bf16(
                        af[mt][kc], bfr[nt], acc[mt][nt], 0, 0, 0);
        }
    }

    // ---- epilogue: store y (fp32), fused GroupNorm partial sums ----
    float sg[4] = {0.f, 0.f, 0.f, 0.f};
    float qg[4] = {0.f, 0.f, 0.f, 0.f};
#pragma unroll
    for (int mt = 0; mt < 4; ++mt) {
#pragma unroll
        for (int nt = 0; nt < 4; ++nt) {
            int ro = 2 * w + (nt >> 1);
            int c0 = (nt & 1) * 16;
            float* yp = y + ((b * 64 + mt * 16 + q * 4) * 65536 +
                             (R0 + ro) * 256 + C0 + c0 + l15);
#pragma unroll
            for (int r = 0; r < 4; ++r) {
                float v = acc[mt][nt][r];
                yp[r * 65536] = v;
                sg[mt] += v;
                qg[mt] += v * v;
            }
        }
    }
    // half-wave (32-lane) shuffle reduction, then 8 LDS atomics per half-wave
#pragma unroll
    for (int mt = 0; mt < 4; ++mt) {
#pragma unroll
        for (int off = 1; off <= 16; off <<= 1) {
            sg[mt] += __shfl_xor(sg[mt], off, 64);
            qg[mt] += __shfl_xor(qg[mt], off, 64);
        }
    }
    if ((lane & 31) == 0) {
        const int gsel = q >> 1;   // 0 for lane 0, 1 for lane 32
#pragma unroll
        for (int mt = 0; mt < 4; ++mt) {
            atomicAdd(&lst[(2 * mt + gsel) * 2 + 0], sg[mt]);
            atomicAdd(&lst[(2 * mt + gsel) * 2 + 1], qg[mt]);
        }
    }
    __syncthreads();
    if (tid < 16) atomicAdd(&stats[b * 16 + tid], lst[tid]);
}

// ---------------------------------------------------------------------------
// Kernel 2 (fallback, verified baseline): VALU-staged conv, used only if the
// workspace is too small for the NHWC buffer.
// ---------------------------------------------------------------------------
#define LDSBYTES (NSLOT * 128)

__global__ __launch_bounds__(256, 3)
void k_conv(const float* __restrict__ x, const unsigned short* __restrict__ wm16,
            float* __restrict__ y, float* __restrict__ stats) {
    __shared__ __align__(16) char smem[LDSBYTES];
    __shared__ float lst[16];

    const int tile = blockIdx.x;          // 0..255
    const int b    = blockIdx.y;          // 0..15
    const int R0   = (tile >> 3) * 8;
    const int C0   = (tile & 7) * 32;
    const int tid  = threadIdx.x;
    const int w    = tid >> 6;            // wave 0..3
    const int lane = tid & 63;
    const int l15  = lane & 15;
    const int q    = lane >> 4;           // 0..3

    if (tid < 16) lst[tid] = 0.0f;

    for (int t = tid; t < NSLOT * 8; t += 256) {
        int chunk = t / NSLOT;
        int slot  = t - chunk * NSLOT;
        int r = slot / 34;
        int c = slot - r * 34;
        int gr = R0 - 1 + r;
        int gc = C0 - 1 + c;
        bool ok = ((unsigned)gr < (unsigned)H_) && ((unsigned)gc < (unsigned)W_);
        const float* xp = x + (((b * 64 + chunk * 8) * 256 + gr) * 256 + gc);
        unsigned u[4];
#pragma unroll
        for (int jj = 0; jj < 4; ++jj) {
            float v0 = ok ? xp[(2 * jj) * 65536] : 0.0f;
            float v1 = ok ? xp[(2 * jj + 1) * 65536] : 0.0f;
            u[jj] = (bf16bits(v1) << 16) | bf16bits(v0);
        }
        *(int4*)(smem + slot * 128 + ((chunk ^ (slot & 7)) << 4)) =
            make_int4(u[0], u[1], u[2], u[3]);
    }
    __syncthreads();

    f32x4 acc[4][4];
#pragma unroll
    for (int mt = 0; mt < 4; ++mt)
#pragma unroll
        for (int nt = 0; nt < 4; ++nt)
            acc[mt][nt] = (f32x4){0.f, 0.f, 0.f, 0.f};

    const unsigned short* wb = wm16 + b * (64 * 9 * 64);

    for (int tap = 0; tap < 9; ++tap) {
        const int ky = tap / 3;
        const int kx = tap - ky * 3;

        bf16x8 af[4][2];
#pragma unroll
        for (int mt = 0; mt < 4; ++mt)
#pragma unroll
            for (int kc = 0; kc < 2; ++kc)
                af[mt][kc] = *(const bf16x8*)(wb +
                    ((mt * 16 + l15) * 9 + tap) * 64 + kc * 32 + q * 8);

#pragma unroll
        for (int kc = 0; kc < 2; ++kc) {
            bf16x8 bfr[4];
#pragma unroll
            for (int nt = 0; nt < 4; ++nt) {
                int ro = 2 * w + (nt >> 1);
                int c0 = (nt & 1) * 16;
                int slot = (ro + ky) * 34 + c0 + kx + l15;
                int chunk = kc * 4 + q;
                bfr[nt] = *(const bf16x8*)(smem + slot * 128 +
                                           ((chunk ^ (slot & 7)) << 4));
            }
#pragma unroll
            for (int mt = 0; mt < 4; ++mt)
#pragma unroll
                for (int nt = 0; nt < 4; ++nt)
                    acc[mt][nt] = __builtin_amdgcn_mfma_f32_16x16x32_bf16(
                        af[mt][kc], bfr[nt], acc[mt][nt], 0, 0, 0);
        }
    }

    float sg[4] = {0.f, 0.f, 0.f, 0.f};
    float qg[4] = {0.f, 0.f, 0.f, 0.f};
#pragma unroll
    for (int mt = 0; mt < 4; ++mt) {
#pragma unroll
        for (int nt = 0; nt < 4; ++nt) {
            int ro = 2 * w + (nt >> 1);
            int c0 = (nt & 1) * 16;
            float* yp = y + ((b * 64 + mt * 16 + q * 4) * 65536 +
                             (R0 + ro) * 256 + C0 + c0 + l15);
#pragma unroll
            for (int r = 0; r < 4; ++r) {
                float v = acc[mt][nt][r];
                yp[r * 65536] = v;
                sg[mt] += v;
                qg[mt] += v * v;
            }
        }
    }
    const int gsel = q >> 1;
#pragma unroll
    for (int mt = 0; mt < 4; ++mt) {
        atomicAdd(&lst[(2 * mt + gsel) * 2 + 0], sg[mt]);
        atomicAdd(&lst[(2 * mt + gsel) * 2 + 1], qg[mt]);
    }
    __syncthreads();
    if (tid < 16) atomicAdd(&stats[b * 16 + tid], lst[tid]);
}

// ---------------------------------------------------------------------------
// Kernel 3: GroupNorm apply + SiLU in place on d_out.
// ---------------------------------------------------------------------------
__global__ __launch_bounds__(256)
void k_norm(float4* __restrict__ y, const float* __restrict__ stats,
            const float* __restrict__ gamma, const float* __restrict__ beta) {
    const int cg = blockIdx.x >> 6;       // b*64 + ch
    const int b  = cg >> 6;
    const int ch = cg & 63;
    const int g  = ch >> 3;

    const float sum = stats[(b * NGROUPS + g) * 2 + 0];
    const float ssq = stats[(b * NGROUPS + g) * 2 + 1];
    const float invN = 1.0f / (float)(CH_PER_G * H_ * W_);
    const float mean = sum * invN;
    const float var  = fmaxf(ssq * invN - mean * mean, 0.0f);
    const float rstd = rsqrtf(var + 1e-5f);
    const float ga = gamma[ch] * rstd;
    const float be = beta[ch] - mean * ga;

    const int idx = blockIdx.x * 256 + threadIdx.x;
    float4 v = y[idx];
    float t;
    t = v.x * ga + be; v.x = t / (1.0f + __expf(-t));
    t = v.y * ga + be; v.y = t / (1.0f + __expf(-t));
    t = v.z * ga + be; v.z = t / (1.0f + __expf(-t));
    t = v.w * ga + be; v.w = t / (1.0f + __expf(-t));
    y[idx] = v;
}

// ---------------------------------------------------------------------------
extern "C" void kernel_launch(void* const* d_in, const int* in_sizes, int n_in,
                              void* d_out, int out_size, void* d_ws, size_t ws_size,
                              hipStream_t stream) {
    const float* x     = (const float*)d_in[0];
    const float* mod   = (const float*)d_in[1];
    const float* kmod  = (const float*)d_in[2];
    const float* cw    = (const float*)d_in[3];
    const float* gamma = (const float*)d_in[4];
    const float* beta  = (const float*)d_in[5];
    float* out = (float*)d_out;

    unsigned short* wm16 = (unsigned short*)d_ws;
    float* stats = (float*)((char*)d_ws + WM16_BYTES);
    unsigned short* xt = (unsigned short*)((char*)d_ws + XT_OFF);

    k_weights<<<dim3(B_ * C_OUT), dim3(64), 0, stream>>>(mod, kmod, cw, wm16);
    hipMemsetAsync(stats, 0, STATS_FLOATS * sizeof(float), stream);

    if (ws_size >= XT_OFF + XT_BYTES) {
        k_border<<<dim3(514), dim3(256), 0, stream>>>(xt);
        k_xpose<<<dim3(8192), dim3(256), 0, stream>>>(x, xt);
        k_conv2<<<dim3(256, B_), dim3(256), 0, stream>>>(xt, wm16, out, stats);
    } else {
        k_conv<<<dim3(256, B_), dim3(256), 0, stream>>>(x, wm16, out, stats);
    }

    k_norm<<<dim3(B_ * C_OUT * 64), dim3(256), 0, stream>>>(
        (float4*)out, stats, gamma, beta);
}